// Round 13
// baseline (289.467 us; speedup 1.0000x reference)
//
#include <hip/hip_runtime.h>

// Chamfer loss: B=8, V=4, N=2048, D=3 fp32.
// final = per_view[0] + sum_v per_view[v]; per_view = mean_b(cham_x + cham_y)
// => weight per (b,v,dir) job = ((v==0)?2:1)/8.
//
// R18 = R14 (17.18us, proven) + T14 staging split. Fusion arc is dead:
// R15 grid.sync hung the graph; R16 atomicAdd broke replay idempotency;
// R17's memset node cost ~13us (fill dispatches are ~39us wall on this
// system regardless of size). Two plain dispatches, as R14.
// Change vs R14: stage_chunk split into {issue 3 float2 loads at chunk top
// (6 regs live)} ... {pack + ds_write AFTER the pr-compute}. HBM latency
// (~300-900cy) hides under ~700cy of MFMA/max3 instead of stalling the wave
// at the chunk top. Prologue reordered: chunk-0 y-loads issue BEFORE the
// A-frag build so both load bursts overlap. (R11's write-late spilled with
// 24 pre-packed regs live; raw y is only 6 regs -- fits (256,2) headroom.)
//
// R14's tail: LDS transpose-reduce in the dead yf buffer ([64][33] f32 pane
// per wave, bank (row+col)%32 conflict-free) instead of the 160-swizzle
// butterfly (-3us vs R7).
//
// Math (absmax 0.0 across R7-R14): dot(x,y) via 4-term bf16 split inside
// mfma_f32_32x32x16_bf16; -0.5|y|^2 folded as fp32-accurate (wh,wl) K-slots
// vs A=1.0. t = x.y - 0.5|y|^2; min d2 <=> max t; d2 = |x|^2 - 2t (|x|^2 fp32).
// K-slot map (A,B share it): k0-2 h*h, k3-5 h*l, k6-8 l*h, k9-10 1*(wh,wl),
// k11-13 l*l, k14-15 zero. C layout: col=lane&31, row=(j&3)+8*(j>>2)+4*(lane>>5).

#define B_ 8
#define V_ 4
#define N_ 2048
#define JOBS 64
#define RPB 256                       // rows per block
#define GRID_ (JOBS * (N_ / RPB))     // 512
#define CHUNK 512                     // cols per LDS chunk
#define NCHUNK (N_ / CHUNK)           // 4
#define CPITCH 24                     // ushorts per col (48 B): 16 data + 8 pad

typedef short bf16x8 __attribute__((ext_vector_type(8)));
typedef float f32x16 __attribute__((ext_vector_type(16)));

__device__ __forceinline__ unsigned short f2bf(float f) {
  union { float f; unsigned u; } v; v.f = f;
  const unsigned r = v.u + 0x7fffu + ((v.u >> 16) & 1u);  // RNE, same as v_cvt
  return (unsigned short)(r >> 16);
}
__device__ __forceinline__ float bf2f(unsigned short h) {
  union { unsigned u; float f; } v; v.u = ((unsigned)h) << 16;
  return v.f;
}

__device__ __forceinline__ void pack_col(float y0, float y1, float y2,
                                         unsigned short* dst) {
  const unsigned short h0 = f2bf(y0), h1 = f2bf(y1), h2 = f2bf(y2);
  const unsigned short l0 = f2bf(y0 - bf2f(h0));
  const unsigned short l1 = f2bf(y1 - bf2f(h1));
  const unsigned short l2 = f2bf(y2 - bf2f(h2));
  const float w = -0.5f * fmaf(y0, y0, fmaf(y1, y1, y2 * y2));
  const unsigned short wh = f2bf(w);
  const unsigned short wl = f2bf(w - bf2f(wh));
  bf16x8 b0, b1;
  b0[0] = (short)h0; b0[1] = (short)h1; b0[2] = (short)h2;   // k0-2
  b0[3] = (short)l0; b0[4] = (short)l1; b0[5] = (short)l2;   // k3-5
  b0[6] = (short)h0; b0[7] = (short)h1;                      // k6-7
  b1[0] = (short)h2;                                         // k8
  b1[1] = (short)wh; b1[2] = (short)wl;                      // k9-10
  b1[3] = (short)l0; b1[4] = (short)l1; b1[5] = (short)l2;   // k11-13
  b1[6] = 0; b1[7] = 0;                                      // k14-15
  *(bf16x8*)(dst) = b0;        // ds_write_b128, 16B-aligned (pitch 48)
  *(bf16x8*)(dst + 8) = b1;
}

__device__ __forceinline__ void pack_two(float2 u0, float2 u1, float2 u2,
                                         unsigned short* dst) {
  pack_col(u0.x, u0.y, u1.x, dst);
  pack_col(u1.y, u2.x, u2.y, dst + CPITCH);
}

__global__ __launch_bounds__(256, 2) void chamfer_main(
    const float* __restrict__ X, const float* __restrict__ T,
    float* __restrict__ bsum) {
  __shared__ unsigned short yf[2][CHUNK * CPITCH];  // 2 x 24 KB
  __shared__ float red4[4];

  // XCD swizzle: physical p -> XCD p&7; XCD x owns logical [x*64,(x+1)*64)
  // = 8 consecutive jobs (y/x panels L2-resident per XCD).
  const int p = blockIdx.x;
  const int bid = (p & 7) * (GRID_ / 8) + (p >> 3);
  const int job = bid >> 3;          // [0,64): 8 blocks per job
  const int rc  = bid & 7;           // row-chunk of 256
  const int pair = job >> 1;
  const int dir  = job & 1;          // 0: rows=X cols=T (cham_x), 1: swapped
  const float* xb = (dir ? T : X) + (size_t)pair * N_ * 3;
  const float* yb = (dir ? X : T) + (size_t)pair * N_ * 3;
  const int t = threadIdx.x;
  const int lane = t & 63;
  const int wv = t >> 6;
  const int lr = lane & 31;          // A-row / B-col within tile
  const int g  = lane >> 5;          // K-group (which 8 k-slots this lane feeds)

  // ---- issue chunk-0 y loads FIRST (latency overlaps A-frag build) ----
  const float2* yp0 = (const float2*)(yb + (size_t)(t * 2) * 3);
  const float2 c0a = yp0[0], c0b = yp0[1], c0c = yp0[2];

  // ---- A fragments: this wave's 64 rows = 2 row-tiles of 32 ----
  bf16x8 afrag[2];
  float xn2[2];
  const int rbase = rc * RPB + wv * 64;
#pragma unroll
  for (int rt = 0; rt < 2; ++rt) {
    const int r = rbase + rt * 32 + lr;
    const float x0 = xb[r * 3 + 0], x1 = xb[r * 3 + 1], x2 = xb[r * 3 + 2];
    xn2[rt] = fmaf(x0, x0, fmaf(x1, x1, x2 * x2));
    const unsigned short h0 = f2bf(x0), h1 = f2bf(x1), h2 = f2bf(x2);
    const unsigned short l0 = f2bf(x0 - bf2f(h0));
    const unsigned short l1 = f2bf(x1 - bf2f(h1));
    const unsigned short l2 = f2bf(x2 - bf2f(h2));
    const unsigned short ONE = 0x3F80;  // bf16 1.0
    bf16x8 a;
    if (g == 0) {  // k0-7
      a[0] = (short)h0; a[1] = (short)h1; a[2] = (short)h2;
      a[3] = (short)h0; a[4] = (short)h1; a[5] = (short)h2;
      a[6] = (short)l0; a[7] = (short)l1;
    } else {       // k8-15
      a[0] = (short)l2; a[1] = (short)ONE; a[2] = (short)ONE;
      a[3] = (short)l0; a[4] = (short)l1; a[5] = (short)l2;
      a[6] = 0; a[7] = 0;
    }
    afrag[rt] = a;
  }

  f32x16 r0, r1;
#pragma unroll
  for (int j = 0; j < 16; ++j) { r0[j] = -1e30f; r1[j] = -1e30f; }

  // ---- pack chunk 0 (loads have landed under the A-frag work) ----
  pack_two(c0a, c0b, c0c, yf[0] + (size_t)(t * 2) * CPITCH);
  __syncthreads();

  for (int ch = 0; ch < NCHUNK; ++ch) {
    // T14 issue-early: next chunk's 3 float2 loads (6 regs live thru compute)
    float2 n0, n1, n2;
    if (ch + 1 < NCHUNK) {
      const float2* yp =
          (const float2*)(yb + (size_t)((ch + 1) * CHUNK + t * 2) * 3);
      n0 = yp[0]; n1 = yp[1]; n2 = yp[2];
    }
    const unsigned short* yfb = yf[ch & 1];
#pragma unroll
    for (int pr = 0; pr < CHUNK / 64; ++pr) {  // 8 col-tile pairs
      const unsigned short* pa = yfb + (size_t)(pr * 64 + lr) * CPITCH + g * 8;
      const bf16x8 bA = *(const bf16x8*)pa;                    // ds_read_b128
      const bf16x8 bB = *(const bf16x8*)(pa + 32 * CPITCH);
      const f32x16 d00 =
          __builtin_amdgcn_mfma_f32_32x32x16_bf16(afrag[0], bA, (f32x16){}, 0, 0, 0);
      const f32x16 d10 =
          __builtin_amdgcn_mfma_f32_32x32x16_bf16(afrag[1], bA, (f32x16){}, 0, 0, 0);
      const f32x16 d01 =
          __builtin_amdgcn_mfma_f32_32x32x16_bf16(afrag[0], bB, (f32x16){}, 0, 0, 0);
      const f32x16 d11 =
          __builtin_amdgcn_mfma_f32_32x32x16_bf16(afrag[1], bB, (f32x16){}, 0, 0, 0);
#pragma unroll
      for (int j = 0; j < 16; ++j) {           // 2 new values per v_max3
        r0[j] = fmaxf(fmaxf(r0[j], d00[j]), d01[j]);
        r1[j] = fmaxf(fmaxf(r1[j], d10[j]), d11[j]);
      }
    }
    // T14 write-late: pack + ds_write after compute (buffer ch^1 was last
    // read in chunk ch-1; the barrier there makes overwrite safe).
    if (ch + 1 < NCHUNK)
      pack_two(n0, n1, n2, yf[(ch + 1) & 1] + (size_t)(t * 2) * CPITCH);
    __syncthreads();  // writes visible; reads of ch done before reuse
  }

  // ---- tail (R14): LDS transpose-reduce in the dead yf buffer. Per-wave
  // pane [64 rows][33 f32]: value (rt,j) of lane -> row rt*32+(j&3)+8*(j>>2)
  // +4*g, col lr. Bank = (row+col)%32: conflict-free writes AND reads.
  // Column 32 holds |x|^2 per row. One barrier, then lane l folds row l.
  float* tw = ((float*)&yf[0][0]) + wv * (64 * 33);  // 8448 B/wave
#pragma unroll
  for (int rt = 0; rt < 2; ++rt) {
#pragma unroll
    for (int j = 0; j < 16; ++j) {
      const int rl = rt * 32 + (j & 3) + 8 * (j >> 2) + 4 * g;
      tw[rl * 33 + lr] = rt ? r1[j] : r0[j];
    }
    // lanes l and l+32 share lr -> same row, same xn2 value: benign dup write
    tw[(rt * 32 + lr) * 33 + 32] = xn2[rt];
  }
  __syncthreads();

  // lane l owns row l of its wave's pane: fold 32 col-maxes + xn2.
  float mx = -1e30f;
#pragma unroll
  for (int c = 0; c < 32; ++c) mx = fmaxf(mx, tw[lane * 33 + c]);
  const float d = fmaf(-2.0f, mx, tw[lane * 33 + 32]);  // min d2 for row

  const int v_ = pair & (V_ - 1);
  float acc = d * (((v_ == 0) ? 2.0f : 1.0f) * (1.0f / (float)B_));
#pragma unroll
  for (int o = 32; o > 0; o >>= 1) acc += __shfl_down(acc, o, 64);
  if (lane == 0) red4[wv] = acc;
  __syncthreads();
  if (t == 0) bsum[bid] = (red4[0] + red4[1]) + (red4[2] + red4[3]);
}

__global__ __launch_bounds__(256) void chamfer_final(
    const float* __restrict__ bsum, float* __restrict__ out) {
  __shared__ float red4[4];
  const int t = threadIdx.x;
  float v = bsum[t] + bsum[t + 256];
#pragma unroll
  for (int o = 32; o > 0; o >>= 1) v += __shfl_down(v, o, 64);
  const int lane = t & 63, wid = t >> 6;
  if (lane == 0) red4[wid] = v;
  __syncthreads();
  if (t == 0) out[0] = (red4[0] + red4[1]) + (red4[2] + red4[3]);
}

extern "C" void kernel_launch(void* const* d_in, const int* in_sizes, int n_in,
                              void* d_out, int out_size, void* d_ws, size_t ws_size,
                              hipStream_t stream) {
  const float* X = (const float*)d_in[0];
  const float* T = (const float*)d_in[1];
  float* out = (float*)d_out;
  float* bsum = (float*)d_ws;  // 512 floats, fully overwritten each launch

  chamfer_main<<<GRID_, 256, 0, stream>>>(X, T, bsum);
  chamfer_final<<<1, 256, 0, stream>>>(bsum, out);
}

// Round 14
// 17.787 us; speedup vs baseline: 16.2737x; 16.2737x over previous
//
#include <hip/hip_runtime.h>

// Chamfer loss: B=8, V=4, N=2048, D=3 fp32.
// final = per_view[0] + sum_v per_view[v]; per_view = mean_b(cham_x + cham_y)
// => weight per (b,v,dir) job = ((v==0)?2:1)/8.
//
// R19 = R14 skeleton + R13's register-disciplined inner loop, at (256,3).
// Spill ledger (R8/R10/R11/R18): any staging value live across the
// unrolled 8-step MFMA body spills at ANY budget; and the unroll-8 body
// itself hoists up to 8 d-tiles (128 acc regs), so it only fits the 256-reg
// (256,2) budget. R13 proved the fix that fits 128 regs WITHOUT spilling:
// unroll 1 + sched_barrier(0) mid-body (caps live d-tiles at 2) + manual
// 1-deep B-frag prefetch. Grafted here onto R14's proven skeleton ->
// (256,3): 3 blocks/CU (LDS 48.5KB x3 = 146KB fits), 12 waves/CU, +50% TLP
// against the measured ~4x latency factor. Staging stays R14-style INLINE
// at chunk top (never concurrent with the MFMA body).
//
// R14's tail: LDS transpose-reduce in the dead yf buffer ([64][33] f32 pane
// per wave, bank (row+col)%32 conflict-free) instead of the 160-swizzle
// butterfly (-3us vs R7). Fusion arc dead (R15 hang / R16 idempotency /
// R17 memset node ~13us): two plain dispatches.
//
// Math (absmax 0.0 across R7-R18): dot(x,y) via 4-term bf16 split inside
// mfma_f32_32x32x16_bf16; -0.5|y|^2 folded as fp32-accurate (wh,wl) K-slots
// vs A=1.0. t = x.y - 0.5|y|^2; min d2 <=> max t; d2 = |x|^2 - 2t (|x|^2 fp32).
// K-slot map (A,B share it): k0-2 h*h, k3-5 h*l, k6-8 l*h, k9-10 1*(wh,wl),
// k11-13 l*l, k14-15 zero. C layout: col=lane&31, row=(j&3)+8*(j>>2)+4*(lane>>5).

#define B_ 8
#define V_ 4
#define N_ 2048
#define JOBS 64
#define RPB 256                       // rows per block
#define GRID_ (JOBS * (N_ / RPB))     // 512
#define CHUNK 512                     // cols per LDS chunk
#define NCHUNK (N_ / CHUNK)           // 4
#define CPITCH 24                     // ushorts per col (48 B): 16 data + 8 pad

typedef short bf16x8 __attribute__((ext_vector_type(8)));
typedef float f32x16 __attribute__((ext_vector_type(16)));

__device__ __forceinline__ unsigned short f2bf(float f) {
  union { float f; unsigned u; } v; v.f = f;
  const unsigned r = v.u + 0x7fffu + ((v.u >> 16) & 1u);  // RNE, same as v_cvt
  return (unsigned short)(r >> 16);
}
__device__ __forceinline__ float bf2f(unsigned short h) {
  union { unsigned u; float f; } v; v.u = ((unsigned)h) << 16;
  return v.f;
}

__device__ __forceinline__ void pack_col(float y0, float y1, float y2,
                                         unsigned short* dst) {
  const unsigned short h0 = f2bf(y0), h1 = f2bf(y1), h2 = f2bf(y2);
  const unsigned short l0 = f2bf(y0 - bf2f(h0));
  const unsigned short l1 = f2bf(y1 - bf2f(h1));
  const unsigned short l2 = f2bf(y2 - bf2f(h2));
  const float w = -0.5f * fmaf(y0, y0, fmaf(y1, y1, y2 * y2));
  const unsigned short wh = f2bf(w);
  const unsigned short wl = f2bf(w - bf2f(wh));
  bf16x8 b0, b1;
  b0[0] = (short)h0; b0[1] = (short)h1; b0[2] = (short)h2;   // k0-2
  b0[3] = (short)l0; b0[4] = (short)l1; b0[5] = (short)l2;   // k3-5
  b0[6] = (short)h0; b0[7] = (short)h1;                      // k6-7
  b1[0] = (short)h2;                                         // k8
  b1[1] = (short)wh; b1[2] = (short)wl;                      // k9-10
  b1[3] = (short)l0; b1[4] = (short)l1; b1[5] = (short)l2;   // k11-13
  b1[6] = 0; b1[7] = 0;                                      // k14-15
  *(bf16x8*)(dst) = b0;        // ds_write_b128, 16B-aligned (pitch 48)
  *(bf16x8*)(dst + 8) = b1;
}

__device__ __forceinline__ void stage_chunk(const float* __restrict__ yb,
                                            unsigned short* __restrict__ dstbuf,
                                            int ch, int t) {
  const int c0 = ch * CHUNK + t * 2;                  // 2 cols per thread
  const float2* yp2 = (const float2*)(yb + (size_t)c0 * 3);  // 8B-aligned
  const float2 u0 = yp2[0], u1 = yp2[1], u2 = yp2[2];
  unsigned short* dst = dstbuf + (size_t)(t * 2) * CPITCH;
  pack_col(u0.x, u0.y, u1.x, dst);
  pack_col(u1.y, u2.x, u2.y, dst + CPITCH);
}

__global__ __launch_bounds__(256, 3) void chamfer_main(
    const float* __restrict__ X, const float* __restrict__ T,
    float* __restrict__ bsum) {
  __shared__ unsigned short yf[2][CHUNK * CPITCH];  // 2 x 24 KB
  __shared__ float red4[4];

  // XCD swizzle: physical p -> XCD p&7; XCD x owns logical [x*64,(x+1)*64)
  // = 8 consecutive jobs (y/x panels L2-resident per XCD).
  const int p = blockIdx.x;
  const int bid = (p & 7) * (GRID_ / 8) + (p >> 3);
  const int job = bid >> 3;          // [0,64): 8 blocks per job
  const int rc  = bid & 7;           // row-chunk of 256
  const int pair = job >> 1;
  const int dir  = job & 1;          // 0: rows=X cols=T (cham_x), 1: swapped
  const float* xb = (dir ? T : X) + (size_t)pair * N_ * 3;
  const float* yb = (dir ? X : T) + (size_t)pair * N_ * 3;
  const int t = threadIdx.x;
  const int lane = t & 63;
  const int wv = t >> 6;
  const int lr = lane & 31;          // A-row / B-col within tile
  const int g  = lane >> 5;          // K-group (which 8 k-slots this lane feeds)

  // ---- A fragments: this wave's 64 rows = 2 row-tiles of 32 ----
  bf16x8 afrag[2];
  float xn2[2];
  const int rbase = rc * RPB + wv * 64;
#pragma unroll
  for (int rt = 0; rt < 2; ++rt) {
    const int r = rbase + rt * 32 + lr;
    const float x0 = xb[r * 3 + 0], x1 = xb[r * 3 + 1], x2 = xb[r * 3 + 2];
    xn2[rt] = fmaf(x0, x0, fmaf(x1, x1, x2 * x2));
    const unsigned short h0 = f2bf(x0), h1 = f2bf(x1), h2 = f2bf(x2);
    const unsigned short l0 = f2bf(x0 - bf2f(h0));
    const unsigned short l1 = f2bf(x1 - bf2f(h1));
    const unsigned short l2 = f2bf(x2 - bf2f(h2));
    const unsigned short ONE = 0x3F80;  // bf16 1.0
    bf16x8 a;
    if (g == 0) {  // k0-7
      a[0] = (short)h0; a[1] = (short)h1; a[2] = (short)h2;
      a[3] = (short)h0; a[4] = (short)h1; a[5] = (short)h2;
      a[6] = (short)l0; a[7] = (short)l1;
    } else {       // k8-15
      a[0] = (short)l2; a[1] = (short)ONE; a[2] = (short)ONE;
      a[3] = (short)l0; a[4] = (short)l1; a[5] = (short)l2;
      a[6] = 0; a[7] = 0;
    }
    afrag[rt] = a;
  }

  f32x16 r0, r1;
#pragma unroll
  for (int j = 0; j < 16; ++j) { r0[j] = -1e30f; r1[j] = -1e30f; }

  stage_chunk(yb, yf[0], 0, t);
  __syncthreads();

  for (int ch = 0; ch < NCHUNK; ++ch) {
    if (ch + 1 < NCHUNK)                       // inline staging (R14-proven):
      stage_chunk(yb, yf[(ch + 1) & 1], ch + 1, t);  // never live in MFMA body
    const unsigned short* yfb = yf[ch & 1];
    const unsigned short* pa0 = yfb + (size_t)lr * CPITCH + g * 8;
    // R13-style fence-disciplined loop: unroll 1 + 1-deep B-frag prefetch;
    // sched_barrier(0) caps live d-tiles at 2 (32 acc regs) -> fits (256,3).
    bf16x8 cA = *(const bf16x8*)pa0;
    bf16x8 cB = *(const bf16x8*)(pa0 + 32 * CPITCH);
#pragma unroll 1
    for (int pr = 0; pr < CHUNK / 64; ++pr) {  // 8 col-tile pairs
      const int nx = (pr + 1) & 7;             // wraps on last iter (harmless)
      const bf16x8 nA = *(const bf16x8*)(pa0 + (size_t)(nx * 64) * CPITCH);
      const bf16x8 nB = *(const bf16x8*)(pa0 + (size_t)(nx * 64 + 32) * CPITCH);
      const f32x16 d00 =
          __builtin_amdgcn_mfma_f32_32x32x16_bf16(afrag[0], cA, (f32x16){}, 0, 0, 0);
      const f32x16 d01 =
          __builtin_amdgcn_mfma_f32_32x32x16_bf16(afrag[0], cB, (f32x16){}, 0, 0, 0);
#pragma unroll
      for (int j = 0; j < 16; ++j) r0[j] = fmaxf(fmaxf(r0[j], d00[j]), d01[j]);
      __builtin_amdgcn_sched_barrier(0);       // d00/d01 dead before d10/d11
      const f32x16 d10 =
          __builtin_amdgcn_mfma_f32_32x32x16_bf16(afrag[1], cA, (f32x16){}, 0, 0, 0);
      const f32x16 d11 =
          __builtin_amdgcn_mfma_f32_32x32x16_bf16(afrag[1], cB, (f32x16){}, 0, 0, 0);
#pragma unroll
      for (int j = 0; j < 16; ++j) r1[j] = fmaxf(fmaxf(r1[j], d10[j]), d11[j]);
      cA = nA;
      cB = nB;
    }
    __syncthreads();  // writes for ch+1 visible; reads of ch done before reuse
  }

  // ---- tail (R14): LDS transpose-reduce in the dead yf buffer. Per-wave
  // pane [64 rows][33 f32]: value (rt,j) of lane -> row rt*32+(j&3)+8*(j>>2)
  // +4*g, col lr. Bank = (row+col)%32: conflict-free writes AND reads.
  // Column 32 holds |x|^2 per row. One barrier, then lane l folds row l.
  float* tw = ((float*)&yf[0][0]) + wv * (64 * 33);  // 8448 B/wave
#pragma unroll
  for (int rt = 0; rt < 2; ++rt) {
#pragma unroll
    for (int j = 0; j < 16; ++j) {
      const int rl = rt * 32 + (j & 3) + 8 * (j >> 2) + 4 * g;
      tw[rl * 33 + lr] = rt ? r1[j] : r0[j];
    }
    // lanes l and l+32 share lr -> same row, same xn2 value: benign dup write
    tw[(rt * 32 + lr) * 33 + 32] = xn2[rt];
  }
  __syncthreads();

  // lane l owns row l of its wave's pane: fold 32 col-maxes + xn2.
  float mx = -1e30f;
#pragma unroll
  for (int c = 0; c < 32; ++c) mx = fmaxf(mx, tw[lane * 33 + c]);
  const float d = fmaf(-2.0f, mx, tw[lane * 33 + 32]);  // min d2 for row

  const int v_ = pair & (V_ - 1);
  float acc = d * (((v_ == 0) ? 2.0f : 1.0f) * (1.0f / (float)B_));
#pragma unroll
  for (int o = 32; o > 0; o >>= 1) acc += __shfl_down(acc, o, 64);
  if (lane == 0) red4[wv] = acc;
  __syncthreads();
  if (t == 0) bsum[bid] = (red4[0] + red4[1]) + (red4[2] + red4[3]);
}

__global__ __launch_bounds__(256) void chamfer_final(
    const float* __restrict__ bsum, float* __restrict__ out) {
  __shared__ float red4[4];
  const int t = threadIdx.x;
  float v = bsum[t] + bsum[t + 256];
#pragma unroll
  for (int o = 32; o > 0; o >>= 1) v += __shfl_down(v, o, 64);
  const int lane = t & 63, wid = t >> 6;
  if (lane == 0) red4[wid] = v;
  __syncthreads();
  if (t == 0) out[0] = (red4[0] + red4[1]) + (red4[2] + red4[3]);
}

extern "C" void kernel_launch(void* const* d_in, const int* in_sizes, int n_in,
                              void* d_out, int out_size, void* d_ws, size_t ws_size,
                              hipStream_t stream) {
  const float* X = (const float*)d_in[0];
  const float* T = (const float*)d_in[1];
  float* out = (float*)d_out;
  float* bsum = (float*)d_ws;  // 512 floats, fully overwritten each launch

  chamfer_main<<<GRID_, 256, 0, stream>>>(X, T, bsum);
  chamfer_final<<<1, 256, 0, stream>>>(bsum, out);
}